// Round 2
// baseline (1395.017 us; speedup 1.0000x reference)
//
#include <hip/hip_runtime.h>
#include <hip/hip_bf16.h>

#define NEG_SLOPE 0.2f

// ---------------- Layer 1: GEMM (N,128)x(128,256) + attention dots ----------------
// One block per node row. 256 threads, each computes one output column.
// Wave h (of 4) reduces a_s[n,h], a_d[n,h] via 64-lane shuffle.
__global__ __launch_bounds__(256) void k_gemm1_att(
    const float* __restrict__ x, const float* __restrict__ W1,
    const float* __restrict__ as1, const float* __restrict__ ad1,
    __hip_bfloat16* __restrict__ h1b, float* __restrict__ a_s1, float* __restrict__ a_d1)
{
    const int n = blockIdx.x, t = threadIdx.x;
    __shared__ float xs[128];
    if (t < 128) xs[t] = x[n * 128 + t];
    __syncthreads();
    float acc = 0.f;
#pragma unroll 8
    for (int k = 0; k < 128; ++k) acc += xs[k] * W1[k * 256 + t];
    h1b[n * 256 + t] = __float2bfloat16(acc);
    float s = acc * as1[t];
    float d = acc * ad1[t];
#pragma unroll
    for (int o = 32; o > 0; o >>= 1) { s += __shfl_down(s, o); d += __shfl_down(d, o); }
    if ((t & 63) == 0) { int h = t >> 6; a_s1[n * 4 + h] = s; a_d1[n * 4 + h] = d; }
}

// ---------------- Layer 1: per-(edge,head) exp + denom accumulate ----------------
// No segment-max pass: softmax is invariant to the per-segment shift; e is O(1)
// by construction so exp() cannot overflow fp32.
__global__ void k_edge1(const int* __restrict__ ei, int E, int M,
    const float* __restrict__ a_s1, const float* __restrict__ a_d1,
    float* __restrict__ ex1, float* __restrict__ den1)
{
    int tid = blockIdx.x * blockDim.x + threadIdx.x;
    if (tid >= M * 4) return;
    int i = tid >> 2, h = tid & 3;
    int src, dst;
    if (i < E) { src = ei[i]; dst = ei[E + i]; } else { src = i - E; dst = src; }
    float e = a_s1[src * 4 + h] + a_d1[dst * 4 + h];
    e = e > 0.f ? e : NEG_SLOPE * e;
    float ex = expf(e);
    ex1[tid] = ex;
    atomicAdd(&den1[dst * 4 + h], ex);
}

// ---------------- Layer 1: scatter-aggregate ----------------
// One block per edge; thread t handles feature t (head = t>>6).
__global__ __launch_bounds__(256) void k_agg1(const int* __restrict__ ei, int E,
    const __hip_bfloat16* __restrict__ h1b, const float* __restrict__ ex1,
    const float* __restrict__ den1, float* __restrict__ agg1)
{
    int i = blockIdx.x, t = threadIdx.x, h = t >> 6;
    int src, dst;
    if (i < E) { src = ei[i]; dst = ei[E + i]; } else { src = i - E; dst = src; }
    float alpha = ex1[i * 4 + h] / den1[dst * 4 + h];
    float v = __bfloat162float(h1b[src * 256 + t]);
    atomicAdd(&agg1[dst * 256 + t], alpha * v);
}

// ---------------- Layer 1 epilogue: +b1, ELU, -> bf16 ----------------
__global__ void k_bias_elu(const float* __restrict__ agg1, const float* __restrict__ b1,
    __hip_bfloat16* __restrict__ h2b, int total)
{
    int idx = blockIdx.x * blockDim.x + threadIdx.x;
    if (idx >= total) return;
    float v = agg1[idx] + b1[idx & 255];
    v = v > 0.f ? v : (expf(v) - 1.f);
    h2b[idx] = __float2bfloat16(v);
}

// ---------------- Layer 2: GEMM (N,256)x(256,64) + attention dots ----------------
__global__ __launch_bounds__(64) void k_gemm2_att(
    const __hip_bfloat16* __restrict__ h2b, const float* __restrict__ W2,
    const float* __restrict__ as2, const float* __restrict__ ad2,
    __hip_bfloat16* __restrict__ h3b, float* __restrict__ a_s2, float* __restrict__ a_d2)
{
    const int n = blockIdx.x, t = threadIdx.x;
    __shared__ float hs[256];
    for (int j = t; j < 256; j += 64) hs[j] = __bfloat162float(h2b[n * 256 + j]);
    __syncthreads();
    float acc = 0.f;
#pragma unroll 8
    for (int k = 0; k < 256; ++k) acc += hs[k] * W2[k * 64 + t];
    h3b[n * 64 + t] = __float2bfloat16(acc);
    float s = acc * as2[t];
    float d = acc * ad2[t];
#pragma unroll
    for (int o = 32; o > 0; o >>= 1) { s += __shfl_down(s, o); d += __shfl_down(d, o); }
    if (t == 0) { a_s2[n] = s; a_d2[n] = d; }
}

// ---------------- Layer 2: per-edge exp + denom ----------------
__global__ void k_edge2(const int* __restrict__ ei, int E, int M,
    const float* __restrict__ a_s2, const float* __restrict__ a_d2,
    float* __restrict__ ex2, float* __restrict__ den2)
{
    int i = blockIdx.x * blockDim.x + threadIdx.x;
    if (i >= M) return;
    int src, dst;
    if (i < E) { src = ei[i]; dst = ei[E + i]; } else { src = i - E; dst = src; }
    float e = a_s2[src] + a_d2[dst];
    e = e > 0.f ? e : NEG_SLOPE * e;
    float ex = expf(e);
    ex2[i] = ex;
    atomicAdd(&den2[dst], ex);
}

// ---------------- Layer 2: scatter-aggregate ----------------
__global__ __launch_bounds__(64) void k_agg2(const int* __restrict__ ei, int E,
    const __hip_bfloat16* __restrict__ h3b, const float* __restrict__ ex2,
    const float* __restrict__ den2, float* __restrict__ agg2)
{
    int i = blockIdx.x, t = threadIdx.x;
    int src, dst;
    if (i < E) { src = ei[i]; dst = ei[E + i]; } else { src = i - E; dst = src; }
    float alpha = ex2[i] / den2[dst];
    atomicAdd(&agg2[dst * 64 + t], alpha * __bfloat162float(h3b[src * 64 + t]));
}

// ---------------- Final: +b2 -> fp32 out ----------------
__global__ void k_out(const float* __restrict__ agg2, const float* __restrict__ b2,
    float* __restrict__ out, int total)
{
    int idx = blockIdx.x * blockDim.x + threadIdx.x;
    if (idx >= total) return;
    out[idx] = agg2[idx] + b2[idx & 63];
}

extern "C" void kernel_launch(void* const* d_in, const int* in_sizes, int n_in,
                              void* d_out, int out_size, void* d_ws, size_t ws_size,
                              hipStream_t stream)
{
    const float* x   = (const float*)d_in[0];
    const int*   ei  = (const int*)d_in[1];
    const float* W1  = (const float*)d_in[2];
    const float* as1 = (const float*)d_in[3];
    const float* ad1 = (const float*)d_in[4];
    const float* b1  = (const float*)d_in[5];
    const float* W2  = (const float*)d_in[6];
    const float* as2 = (const float*)d_in[7];
    const float* ad2 = (const float*)d_in[8];
    const float* b2  = (const float*)d_in[9];
    float* out = (float*)d_out;

    const int N = in_sizes[0] / 128;      // 50000
    const int E = in_sizes[1] / 2;        // 800000
    const int M = E + N;                  // edges + self loops

    // ---- workspace layout (all offsets 256B-aligned), total ~118 MB ----
    char* w = (char*)d_ws;
    size_t o = 0;
    auto alloc = [&](size_t bytes) { size_t r = o; o = (o + bytes + 255) & ~(size_t)255; return r; };
    size_t h1b_off  = alloc((size_t)N * 256 * 2);   // bf16 h1       25.6 MB (dead after k_agg1)
    size_t as1_off  = alloc((size_t)N * 4 * 4);
    size_t ad1_off  = alloc((size_t)N * 4 * 4);
    size_t den1_off = alloc((size_t)N * 4 * 4);
    size_t ex1_off  = alloc((size_t)M * 4 * 4);     // 13.6 MB
    size_t agg1_off = alloc((size_t)N * 256 * 4);   // 51.2 MB
    size_t h2b_off  = alloc((size_t)N * 256 * 2);   // 25.6 MB
    // layer-2 buffers aliased over h1b region (23.3 MB <= 25.6 MB), used only after h1b is dead
    size_t p = h1b_off;
    auto alias = [&](size_t bytes) { size_t r = p; p = (p + bytes + 255) & ~(size_t)255; return r; };
    size_t h3b_off  = alias((size_t)N * 64 * 2);    // 6.4 MB
    size_t as2_off  = alias((size_t)N * 4);
    size_t ad2_off  = alias((size_t)N * 4);
    size_t den2_off = alias((size_t)N * 4);
    size_t ex2_off  = alias((size_t)M * 4);         // 3.4 MB
    size_t agg2_off = alias((size_t)N * 64 * 4);    // 12.8 MB

    __hip_bfloat16* h1b = (__hip_bfloat16*)(w + h1b_off);
    float* a_s1 = (float*)(w + as1_off);
    float* a_d1 = (float*)(w + ad1_off);
    float* den1 = (float*)(w + den1_off);
    float* ex1  = (float*)(w + ex1_off);
    float* agg1 = (float*)(w + agg1_off);
    __hip_bfloat16* h2b = (__hip_bfloat16*)(w + h2b_off);
    __hip_bfloat16* h3b = (__hip_bfloat16*)(w + h3b_off);
    float* a_s2 = (float*)(w + as2_off);
    float* a_d2 = (float*)(w + ad2_off);
    float* den2 = (float*)(w + den2_off);
    float* ex2  = (float*)(w + ex2_off);
    float* agg2 = (float*)(w + agg2_off);

    // ---- layer 1 ----
    hipMemsetAsync(den1, 0, (size_t)N * 4 * 4, stream);
    hipMemsetAsync(agg1, 0, (size_t)N * 256 * 4, stream);
    k_gemm1_att<<<N, 256, 0, stream>>>(x, W1, as1, ad1, h1b, a_s1, a_d1);
    k_edge1<<<(M * 4 + 255) / 256, 256, 0, stream>>>(ei, E, M, a_s1, a_d1, ex1, den1);
    k_agg1<<<M, 256, 0, stream>>>(ei, E, h1b, ex1, den1, agg1);
    k_bias_elu<<<(N * 256 + 255) / 256, 256, 0, stream>>>(agg1, b1, h2b, N * 256);

    // ---- layer 2 (alias region is free only after k_agg1 has read h1b) ----
    hipMemsetAsync(den2, 0, (size_t)N * 4, stream);
    hipMemsetAsync(agg2, 0, (size_t)N * 64 * 4, stream);
    k_gemm2_att<<<N, 64, 0, stream>>>(h2b, W2, as2, ad2, h3b, a_s2, a_d2);
    k_edge2<<<(M + 255) / 256, 256, 0, stream>>>(ei, E, M, a_s2, a_d2, ex2, den2);
    k_agg2<<<M, 64, 0, stream>>>(ei, E, h3b, ex2, den2, agg2);
    k_out<<<(N * 64 + 255) / 256, 256, 0, stream>>>(agg2, b2, out, N * 64);
}

// Round 3
// 549.453 us; speedup vs baseline: 2.5389x; 2.5389x over previous
//
#include <hip/hip_runtime.h>
#include <hip/hip_bf16.h>

#define NEG_SLOPE 0.2f

// ============ Layer 1 GEMM: (N,128)x(128,256), 8 nodes/block ============
// 256 threads; thread t = output column. W1 re-read once per 8 nodes.
__global__ __launch_bounds__(256) void k_gemm1_att(
    const float* __restrict__ x, const float* __restrict__ W1,
    const float* __restrict__ as1, const float* __restrict__ ad1,
    __hip_bfloat16* __restrict__ h1b, float* __restrict__ a_s1, float* __restrict__ a_d1)
{
    const int n0 = blockIdx.x * 8, t = threadIdx.x;
    __shared__ float xs[8 * 128];
    ((float4*)xs)[t] = ((const float4*)(x + (size_t)n0 * 128))[t];  // 1024 floats
    __syncthreads();
    float acc[8] = {0.f, 0.f, 0.f, 0.f, 0.f, 0.f, 0.f, 0.f};
    const float4* xsv = (const float4*)xs;
#pragma unroll 4
    for (int kb = 0; kb < 32; ++kb) {
        float w0 = W1[(4 * kb + 0) * 256 + t];
        float w1 = W1[(4 * kb + 1) * 256 + t];
        float w2 = W1[(4 * kb + 2) * 256 + t];
        float w3 = W1[(4 * kb + 3) * 256 + t];
#pragma unroll
        for (int r = 0; r < 8; ++r) {
            float4 xv = xsv[r * 32 + kb];
            acc[r] += xv.x * w0 + xv.y * w1 + xv.z * w2 + xv.w * w3;
        }
    }
    float vas = as1[t], vad = ad1[t];
    int h = t >> 6;
#pragma unroll
    for (int r = 0; r < 8; ++r) {
        h1b[(size_t)(n0 + r) * 256 + t] = __float2bfloat16(acc[r]);
        float s = acc[r] * vas, d = acc[r] * vad;
#pragma unroll
        for (int o = 32; o > 0; o >>= 1) { s += __shfl_down(s, o); d += __shfl_down(d, o); }
        if ((t & 63) == 0) { a_s1[(n0 + r) * 4 + h] = s; a_d1[(n0 + r) * 4 + h] = d; }
    }
}

// ============ CSR build ============
__global__ void k_hist(const int* __restrict__ ei, int E, int M, int* __restrict__ deg)
{
    int i = blockIdx.x * blockDim.x + threadIdx.x;
    if (i >= M) return;
    int dst = (i < E) ? ei[E + i] : (i - E);
    atomicAdd(&deg[dst], 1);
}

__global__ __launch_bounds__(256) void k_scan1(const int* __restrict__ deg, int N,
    int* __restrict__ excl, int* __restrict__ bsum)
{
    __shared__ int s[256];
    int t = threadIdx.x, i = blockIdx.x * 256 + t;
    int v = (i < N) ? deg[i] : 0;
    s[t] = v; __syncthreads();
#pragma unroll
    for (int o = 1; o < 256; o <<= 1) {
        int x = (t >= o) ? s[t - o] : 0;
        __syncthreads();
        s[t] += x;
        __syncthreads();
    }
    if (i < N) excl[i] = s[t] - v;
    if (t == 255) bsum[blockIdx.x] = s[255];
}

__global__ __launch_bounds__(256) void k_scan2(const int* __restrict__ bsum, int NB,
    int* __restrict__ boff)
{
    __shared__ int s[256];
    int t = threadIdx.x;
    int v = (t < NB) ? bsum[t] : 0;
    s[t] = v; __syncthreads();
#pragma unroll
    for (int o = 1; o < 256; o <<= 1) {
        int x = (t >= o) ? s[t - o] : 0;
        __syncthreads();
        s[t] += x;
        __syncthreads();
    }
    if (t < NB) boff[t] = s[t] - v;
}

__global__ void k_scan3(const int* __restrict__ excl, const int* __restrict__ boff,
    int N, int M, int* __restrict__ rowptr)
{
    int i = blockIdx.x * blockDim.x + threadIdx.x;
    if (i < N) rowptr[i] = excl[i] + boff[i >> 8];
    if (i == 0) rowptr[N] = M;
}

__global__ void k_scatter(const int* __restrict__ ei, int E, int M,
    const int* __restrict__ rowptr, int* __restrict__ cnt, int* __restrict__ csr_src)
{
    int i = blockIdx.x * blockDim.x + threadIdx.x;
    if (i >= M) return;
    int src, dst;
    if (i < E) { src = ei[i]; dst = ei[E + i]; } else { src = i - E; dst = src; }
    int pos = rowptr[dst] + atomicAdd(&cnt[dst], 1);
    csr_src[pos] = src;
}

// ============ Layer 1 edge pass (CSR): ex per slot + den per dst, no atomics ====
// Softmax shift skipped: invariant, and e is O(1) -> no fp32 overflow.
__global__ __launch_bounds__(64) void k_edge1_csr(const int* __restrict__ rowptr,
    const int* __restrict__ csr_src, const float* __restrict__ a_s1,
    const float* __restrict__ a_d1, float* __restrict__ ex1, float* __restrict__ den1)
{
    int dst = blockIdx.x, lane = threadIdx.x;
    int start = rowptr[dst], end = rowptr[dst + 1];
    float4 ad = ((const float4*)a_d1)[dst];
    float4 den = make_float4(0.f, 0.f, 0.f, 0.f);
    for (int j = start + lane; j < end; j += 64) {
        int src = csr_src[j];
        float4 as = ((const float4*)a_s1)[src];
        float e0 = as.x + ad.x; e0 = e0 > 0.f ? e0 : NEG_SLOPE * e0;
        float e1 = as.y + ad.y; e1 = e1 > 0.f ? e1 : NEG_SLOPE * e1;
        float e2 = as.z + ad.z; e2 = e2 > 0.f ? e2 : NEG_SLOPE * e2;
        float e3 = as.w + ad.w; e3 = e3 > 0.f ? e3 : NEG_SLOPE * e3;
        float4 ex = make_float4(expf(e0), expf(e1), expf(e2), expf(e3));
        ((float4*)ex1)[j] = ex;
        den.x += ex.x; den.y += ex.y; den.z += ex.z; den.w += ex.w;
    }
#pragma unroll
    for (int o = 32; o > 0; o >>= 1) {
        den.x += __shfl_down(den.x, o); den.y += __shfl_down(den.y, o);
        den.z += __shfl_down(den.z, o); den.w += __shfl_down(den.w, o);
    }
    if (lane == 0) ((float4*)den1)[dst] = den;
}

// ============ Layer 1 aggregate (CSR, no atomics) + bias + ELU -> h2b ============
__global__ __launch_bounds__(256) void k_agg1_csr(const int* __restrict__ rowptr,
    const int* __restrict__ csr_src, const __hip_bfloat16* __restrict__ h1b,
    const float* __restrict__ ex1, const float* __restrict__ den1,
    const float* __restrict__ b1, __hip_bfloat16* __restrict__ h2b)
{
    int dst = blockIdx.x, t = threadIdx.x, h = t >> 6;
    int start = rowptr[dst], end = rowptr[dst + 1];
    float rden = 1.0f / den1[dst * 4 + h];
    float acc = 0.f;
    int j = start;
    for (; j + 1 < end; j += 2) {   // 2-wide: two gathers in flight
        int s0 = csr_src[j], s1 = csr_src[j + 1];
        float al0 = ex1[j * 4 + h] * rden;
        float al1 = ex1[(j + 1) * 4 + h] * rden;
        float v0 = __bfloat162float(h1b[(size_t)s0 * 256 + t]);
        float v1 = __bfloat162float(h1b[(size_t)s1 * 256 + t]);
        acc += al0 * v0 + al1 * v1;
    }
    if (j < end) {
        int s0 = csr_src[j];
        acc += ex1[j * 4 + h] * rden * __bfloat162float(h1b[(size_t)s0 * 256 + t]);
    }
    float v = acc + b1[t];
    v = v > 0.f ? v : (expf(v) - 1.f);   // ELU
    h2b[(size_t)dst * 256 + t] = __float2bfloat16(v);
}

// ============ Layer 2 GEMM: (N,256)x(256,64), 16 nodes/block, 64 threads ============
__global__ __launch_bounds__(64) void k_gemm2_att(
    const __hip_bfloat16* __restrict__ h2b, const float* __restrict__ W2,
    const float* __restrict__ as2, const float* __restrict__ ad2,
    __hip_bfloat16* __restrict__ h3b, float* __restrict__ a_s2, float* __restrict__ a_d2)
{
    const int n0 = blockIdx.x * 16, t = threadIdx.x;
    __shared__ float hs[16 * 256];
    const __hip_bfloat162* hp = (const __hip_bfloat162*)(h2b + (size_t)n0 * 256);
    for (int i = t; i < 2048; i += 64) {
        __hip_bfloat162 p = hp[i];
        hs[2 * i]     = __bfloat162float(p.x);
        hs[2 * i + 1] = __bfloat162float(p.y);
    }
    __syncthreads();
    float acc[16];
#pragma unroll
    for (int r = 0; r < 16; ++r) acc[r] = 0.f;
    const float4* hsv = (const float4*)hs;
#pragma unroll 4
    for (int kb = 0; kb < 64; ++kb) {
        float w0 = W2[(4 * kb + 0) * 64 + t];
        float w1 = W2[(4 * kb + 1) * 64 + t];
        float w2 = W2[(4 * kb + 2) * 64 + t];
        float w3 = W2[(4 * kb + 3) * 64 + t];
#pragma unroll
        for (int r = 0; r < 16; ++r) {
            float4 hv = hsv[r * 64 + kb];
            acc[r] += hv.x * w0 + hv.y * w1 + hv.z * w2 + hv.w * w3;
        }
    }
    float vas = as2[t], vad = ad2[t];
#pragma unroll
    for (int r = 0; r < 16; ++r) {
        h3b[(size_t)(n0 + r) * 64 + t] = __float2bfloat16(acc[r]);
        float s = acc[r] * vas, d = acc[r] * vad;
#pragma unroll
        for (int o = 32; o > 0; o >>= 1) { s += __shfl_down(s, o); d += __shfl_down(d, o); }
        if (t == 0) { a_s2[n0 + r] = s; a_d2[n0 + r] = d; }
    }
}

// ============ Layer 2 edge pass (CSR) ============
__global__ __launch_bounds__(64) void k_edge2_csr(const int* __restrict__ rowptr,
    const int* __restrict__ csr_src, const float* __restrict__ a_s2,
    const float* __restrict__ a_d2, float* __restrict__ ex2, float* __restrict__ den2)
{
    int dst = blockIdx.x, lane = threadIdx.x;
    int start = rowptr[dst], end = rowptr[dst + 1];
    float ad = a_d2[dst];
    float den = 0.f;
    for (int j = start + lane; j < end; j += 64) {
        float e = a_s2[csr_src[j]] + ad;
        e = e > 0.f ? e : NEG_SLOPE * e;
        float ex = expf(e);
        ex2[j] = ex;
        den += ex;
    }
#pragma unroll
    for (int o = 32; o > 0; o >>= 1) den += __shfl_down(den, o);
    if (lane == 0) den2[dst] = den;
}

// ============ Layer 2 aggregate (CSR) + b2 -> out ============
__global__ __launch_bounds__(64) void k_agg2_csr(const int* __restrict__ rowptr,
    const int* __restrict__ csr_src, const __hip_bfloat16* __restrict__ h3b,
    const float* __restrict__ ex2, const float* __restrict__ den2,
    const float* __restrict__ b2, float* __restrict__ out)
{
    int dst = blockIdx.x, t = threadIdx.x;
    int start = rowptr[dst], end = rowptr[dst + 1];
    float rden = 1.0f / den2[dst];
    float acc = 0.f;
    int j = start;
    for (; j + 1 < end; j += 2) {
        int s0 = csr_src[j], s1 = csr_src[j + 1];
        float al0 = ex2[j] * rden, al1 = ex2[j + 1] * rden;
        float v0 = __bfloat162float(h3b[(size_t)s0 * 64 + t]);
        float v1 = __bfloat162float(h3b[(size_t)s1 * 64 + t]);
        acc += al0 * v0 + al1 * v1;
    }
    if (j < end)
        acc += ex2[j] * rden * __bfloat162float(h3b[(size_t)csr_src[j] * 64 + t]);
    out[(size_t)dst * 64 + t] = acc + b2[t];
}

extern "C" void kernel_launch(void* const* d_in, const int* in_sizes, int n_in,
                              void* d_out, int out_size, void* d_ws, size_t ws_size,
                              hipStream_t stream)
{
    const float* x   = (const float*)d_in[0];
    const int*   ei  = (const int*)d_in[1];
    const float* W1  = (const float*)d_in[2];
    const float* as1 = (const float*)d_in[3];
    const float* ad1 = (const float*)d_in[4];
    const float* b1  = (const float*)d_in[5];
    const float* W2  = (const float*)d_in[6];
    const float* as2 = (const float*)d_in[7];
    const float* ad2 = (const float*)d_in[8];
    const float* b2  = (const float*)d_in[9];
    float* out = (float*)d_out;

    const int N = in_sizes[0] / 128;      // 50000
    const int E = in_sizes[1] / 2;        // 800000
    const int M = E + N;                  // edges + self loops
    const int NB = (N + 255) / 256;       // 196 scan blocks

    // ---- workspace layout (256B-aligned), ~80 MB ----
    char* w = (char*)d_ws;
    size_t o = 0;
    auto alloc = [&](size_t bytes) { size_t r = o; o = (o + bytes + 255) & ~(size_t)255; return r; };
    __hip_bfloat16* h1b   = (__hip_bfloat16*)(w + alloc((size_t)N * 256 * 2)); // 25.6 MB
    float* a_s1           = (float*)(w + alloc((size_t)N * 4 * 4));
    float* a_d1           = (float*)(w + alloc((size_t)N * 4 * 4));
    float* den1           = (float*)(w + alloc((size_t)N * 4 * 4));
    float* ex1            = (float*)(w + alloc((size_t)M * 4 * 4));            // 13.6 MB
    __hip_bfloat16* h2b   = (__hip_bfloat16*)(w + alloc((size_t)N * 256 * 2)); // 25.6 MB
    __hip_bfloat16* h3b   = (__hip_bfloat16*)(w + alloc((size_t)N * 64 * 2));  // 6.4 MB
    float* a_s2           = (float*)(w + alloc((size_t)N * 4));
    float* a_d2           = (float*)(w + alloc((size_t)N * 4));
    float* den2           = (float*)(w + alloc((size_t)N * 4));
    float* ex2            = (float*)(w + alloc((size_t)M * 4));                // 3.4 MB
    int* deg              = (int*)(w + alloc((size_t)N * 4));
    int* cnt              = (int*)(w + alloc((size_t)N * 4));
    int* rowptr           = (int*)(w + alloc((size_t)(N + 1) * 4));
    int* excl             = (int*)(w + alloc((size_t)N * 4));
    int* bsum             = (int*)(w + alloc((size_t)NB * 4));
    int* boff             = (int*)(w + alloc((size_t)NB * 4));
    int* csr_src          = (int*)(w + alloc((size_t)M * 4));                  // 3.4 MB

    // ---- CSR build (shared by both layers) ----
    hipMemsetAsync(deg, 0, (size_t)N * 4, stream);
    hipMemsetAsync(cnt, 0, (size_t)N * 4, stream);
    k_hist<<<(M + 255) / 256, 256, 0, stream>>>(ei, E, M, deg);
    k_scan1<<<NB, 256, 0, stream>>>(deg, N, excl, bsum);
    k_scan2<<<1, 256, 0, stream>>>(bsum, NB, boff);
    k_scan3<<<NB, 256, 0, stream>>>(excl, boff, N, M, rowptr);
    k_scatter<<<(M + 255) / 256, 256, 0, stream>>>(ei, E, M, rowptr, cnt, csr_src);

    // ---- layer 1 ----
    k_gemm1_att<<<N / 8, 256, 0, stream>>>(x, W1, as1, ad1, h1b, a_s1, a_d1);
    k_edge1_csr<<<N, 64, 0, stream>>>(rowptr, csr_src, a_s1, a_d1, ex1, den1);
    k_agg1_csr<<<N, 256, 0, stream>>>(rowptr, csr_src, h1b, ex1, den1, b1, h2b);

    // ---- layer 2 ----
    k_gemm2_att<<<(N + 15) / 16, 64, 0, stream>>>(h2b, W2, as2, ad2, h3b, a_s2, a_d2);
    k_edge2_csr<<<N, 64, 0, stream>>>(rowptr, csr_src, a_s2, a_d2, ex2, den2);
    k_agg2_csr<<<N, 64, 0, stream>>>(rowptr, csr_src, h3b, ex2, den2, b2, out);
}

// Round 4
// 460.662 us; speedup vs baseline: 3.0283x; 1.1927x over previous
//
#include <hip/hip_runtime.h>
#include <hip/hip_bf16.h>

#define NEG_SLOPE 0.2f

// ============ Layer 1 GEMM: (N,128)x(128,256), 8 nodes/block ============
__global__ __launch_bounds__(256) void k_gemm1_att(
    const float* __restrict__ x, const float* __restrict__ W1,
    const float* __restrict__ as1, const float* __restrict__ ad1,
    __hip_bfloat16* __restrict__ h1b, float* __restrict__ a_s1, float* __restrict__ a_d1)
{
    const int n0 = blockIdx.x * 8, t = threadIdx.x;
    __shared__ float xs[8 * 128];
    ((float4*)xs)[t] = ((const float4*)(x + (size_t)n0 * 128))[t];
    __syncthreads();
    float acc[8] = {0.f, 0.f, 0.f, 0.f, 0.f, 0.f, 0.f, 0.f};
    const float4* xsv = (const float4*)xs;
#pragma unroll 4
    for (int kb = 0; kb < 32; ++kb) {
        float w0 = W1[(4 * kb + 0) * 256 + t];
        float w1 = W1[(4 * kb + 1) * 256 + t];
        float w2 = W1[(4 * kb + 2) * 256 + t];
        float w3 = W1[(4 * kb + 3) * 256 + t];
#pragma unroll
        for (int r = 0; r < 8; ++r) {
            float4 xv = xsv[r * 32 + kb];
            acc[r] += xv.x * w0 + xv.y * w1 + xv.z * w2 + xv.w * w3;
        }
    }
    float vas = as1[t], vad = ad1[t];
    int h = t >> 6;
#pragma unroll
    for (int r = 0; r < 8; ++r) {
        h1b[(size_t)(n0 + r) * 256 + t] = __float2bfloat16(acc[r]);
        float s = acc[r] * vas, d = acc[r] * vad;
#pragma unroll
        for (int o = 32; o > 0; o >>= 1) { s += __shfl_down(s, o); d += __shfl_down(d, o); }
        if ((t & 63) == 0) { a_s1[(n0 + r) * 4 + h] = s; a_d1[(n0 + r) * 4 + h] = d; }
    }
}

// ============ CSR build ============
__global__ void k_hist(const int* __restrict__ ei, int E, int M, int* __restrict__ deg)
{
    int i = blockIdx.x * blockDim.x + threadIdx.x;
    if (i >= M) return;
    int dst = (i < E) ? ei[E + i] : (i - E);
    atomicAdd(&deg[dst], 1);
}

__global__ __launch_bounds__(256) void k_scan1(const int* __restrict__ deg, int N,
    int* __restrict__ excl, int* __restrict__ bsum)
{
    __shared__ int s[256];
    int t = threadIdx.x, i = blockIdx.x * 256 + t;
    int v = (i < N) ? deg[i] : 0;
    s[t] = v; __syncthreads();
#pragma unroll
    for (int o = 1; o < 256; o <<= 1) {
        int x = (t >= o) ? s[t - o] : 0;
        __syncthreads();
        s[t] += x;
        __syncthreads();
    }
    if (i < N) excl[i] = s[t] - v;
    if (t == 255) bsum[blockIdx.x] = s[255];
}

__global__ __launch_bounds__(256) void k_scan2(const int* __restrict__ bsum, int NB,
    int* __restrict__ boff)
{
    __shared__ int s[256];
    int t = threadIdx.x;
    int v = (t < NB) ? bsum[t] : 0;
    s[t] = v; __syncthreads();
#pragma unroll
    for (int o = 1; o < 256; o <<= 1) {
        int x = (t >= o) ? s[t - o] : 0;
        __syncthreads();
        s[t] += x;
        __syncthreads();
    }
    if (t < NB) boff[t] = s[t] - v;
}

__global__ void k_scan3(const int* __restrict__ excl, const int* __restrict__ boff,
    int N, int M, int* __restrict__ rowptr)
{
    int i = blockIdx.x * blockDim.x + threadIdx.x;
    if (i < N) rowptr[i] = excl[i] + boff[i >> 8];
    if (i == 0) rowptr[N] = M;
}

__global__ void k_scatter(const int* __restrict__ ei, int E, int M,
    const int* __restrict__ rowptr, int* __restrict__ cnt, int* __restrict__ csr_src)
{
    int i = blockIdx.x * blockDim.x + threadIdx.x;
    if (i >= M) return;
    int src, dst;
    if (i < E) { src = ei[i]; dst = ei[E + i]; } else { src = i - E; dst = src; }
    int pos = rowptr[dst] + atomicAdd(&cnt[dst], 1);
    csr_src[pos] = src;
}

// ============ Layer 1 fused softmax+aggregate+bias+ELU ============
// One dst per block, 128 threads = 2 cols/thread (bf162). Per chunk of 128
// neighbors: phase A computes ex[4 heads] -> LDS + per-thread den partials;
// phase B accumulates UNNORMALIZED weighted sum (divide by den at the end —
// softmax shift skipped: invariant, e is O(1) so no fp32 overflow).
__global__ __launch_bounds__(128) void k_agg1_fused(const int* __restrict__ rowptr,
    const int* __restrict__ csr_src, const float* __restrict__ a_s1,
    const float* __restrict__ a_d1, const __hip_bfloat16* __restrict__ h1b,
    const float* __restrict__ b1, __hip_bfloat16* __restrict__ h2b)
{
    const int dst = blockIdx.x, t = threadIdx.x;
    const int h = t >> 5;                 // head for cols {2t, 2t+1}
    const int start = rowptr[dst], end = rowptr[dst + 1];
    __shared__ int   s_src[128];
    __shared__ float s_ex[128][4];
    __shared__ float s_part[2][4];
    float4 ad = ((const float4*)a_d1)[dst];
    float d0 = 0.f, d1 = 0.f, d2 = 0.f, d3 = 0.f;
    float accx = 0.f, accy = 0.f;

    for (int base = start; base < end; base += 128) {
        int nloc = end - base; if (nloc > 128) nloc = 128;
        if (t < nloc) {
            int src = csr_src[base + t];
            s_src[t] = src;
            float4 as = ((const float4*)a_s1)[src];
            float e0 = as.x + ad.x; e0 = e0 > 0.f ? e0 : NEG_SLOPE * e0;
            float e1 = as.y + ad.y; e1 = e1 > 0.f ? e1 : NEG_SLOPE * e1;
            float e2 = as.z + ad.z; e2 = e2 > 0.f ? e2 : NEG_SLOPE * e2;
            float e3 = as.w + ad.w; e3 = e3 > 0.f ? e3 : NEG_SLOPE * e3;
            float x0 = expf(e0), x1 = expf(e1), x2 = expf(e2), x3 = expf(e3);
            s_ex[t][0] = x0; s_ex[t][1] = x1; s_ex[t][2] = x2; s_ex[t][3] = x3;
            d0 += x0; d1 += x1; d2 += x2; d3 += x3;
        }
        __syncthreads();
        int j = 0;
        for (; j + 3 < nloc; j += 4) {      // 4 gathers in flight
            const __hip_bfloat162* pA = (const __hip_bfloat162*)(h1b + (size_t)s_src[j]     * 256);
            const __hip_bfloat162* pB = (const __hip_bfloat162*)(h1b + (size_t)s_src[j + 1] * 256);
            const __hip_bfloat162* pC = (const __hip_bfloat162*)(h1b + (size_t)s_src[j + 2] * 256);
            const __hip_bfloat162* pD = (const __hip_bfloat162*)(h1b + (size_t)s_src[j + 3] * 256);
            __hip_bfloat162 vA = pA[t], vB = pB[t], vC = pC[t], vD = pD[t];
            float eA = s_ex[j][h], eB = s_ex[j + 1][h], eC = s_ex[j + 2][h], eD = s_ex[j + 3][h];
            accx += eA * __bfloat162float(vA.x) + eB * __bfloat162float(vB.x)
                  + eC * __bfloat162float(vC.x) + eD * __bfloat162float(vD.x);
            accy += eA * __bfloat162float(vA.y) + eB * __bfloat162float(vB.y)
                  + eC * __bfloat162float(vC.y) + eD * __bfloat162float(vD.y);
        }
        for (; j < nloc; ++j) {
            const __hip_bfloat162* pA = (const __hip_bfloat162*)(h1b + (size_t)s_src[j] * 256);
            __hip_bfloat162 vA = pA[t];
            float eA = s_ex[j][h];
            accx += eA * __bfloat162float(vA.x);
            accy += eA * __bfloat162float(vA.y);
        }
        __syncthreads();
    }
    // reduce den partials (each thread holds its own neighbors' contribution)
#pragma unroll
    for (int o = 32; o > 0; o >>= 1) {
        d0 += __shfl_down(d0, o); d1 += __shfl_down(d1, o);
        d2 += __shfl_down(d2, o); d3 += __shfl_down(d3, o);
    }
    if ((t & 63) == 0) {
        int wv = t >> 6;
        s_part[wv][0] = d0; s_part[wv][1] = d1; s_part[wv][2] = d2; s_part[wv][3] = d3;
    }
    __syncthreads();
    float inv = 1.0f / (s_part[0][h] + s_part[1][h]);
    float2 bb = ((const float2*)b1)[t];
    float v0 = accx * inv + bb.x; v0 = v0 > 0.f ? v0 : (expf(v0) - 1.f);
    float v1 = accy * inv + bb.y; v1 = v1 > 0.f ? v1 : (expf(v1) - 1.f);
    __hip_bfloat162 o2; o2.x = __float2bfloat16(v0); o2.y = __float2bfloat16(v1);
    ((__hip_bfloat162*)(h2b + (size_t)dst * 256))[t] = o2;
}

// ============ Layer 2 GEMM: (N,256)x(256,64), 16 nodes/block ============
__global__ __launch_bounds__(64) void k_gemm2_att(
    const __hip_bfloat16* __restrict__ h2b, const float* __restrict__ W2,
    const float* __restrict__ as2, const float* __restrict__ ad2,
    __hip_bfloat16* __restrict__ h3b, float* __restrict__ a_s2, float* __restrict__ a_d2)
{
    const int n0 = blockIdx.x * 16, t = threadIdx.x;
    __shared__ float hs[16 * 256];
    const __hip_bfloat162* hp = (const __hip_bfloat162*)(h2b + (size_t)n0 * 256);
    for (int i = t; i < 2048; i += 64) {
        __hip_bfloat162 p = hp[i];
        hs[2 * i]     = __bfloat162float(p.x);
        hs[2 * i + 1] = __bfloat162float(p.y);
    }
    __syncthreads();
    float acc[16];
#pragma unroll
    for (int r = 0; r < 16; ++r) acc[r] = 0.f;
    const float4* hsv = (const float4*)hs;
#pragma unroll 4
    for (int kb = 0; kb < 64; ++kb) {
        float w0 = W2[(4 * kb + 0) * 64 + t];
        float w1 = W2[(4 * kb + 1) * 64 + t];
        float w2 = W2[(4 * kb + 2) * 64 + t];
        float w3 = W2[(4 * kb + 3) * 64 + t];
#pragma unroll
        for (int r = 0; r < 16; ++r) {
            float4 hv = hsv[r * 64 + kb];
            acc[r] += hv.x * w0 + hv.y * w1 + hv.z * w2 + hv.w * w3;
        }
    }
    float vas = as2[t], vad = ad2[t];
#pragma unroll
    for (int r = 0; r < 16; ++r) {
        h3b[(size_t)(n0 + r) * 64 + t] = __float2bfloat16(acc[r]);
        float s = acc[r] * vas, d = acc[r] * vad;
#pragma unroll
        for (int o = 32; o > 0; o >>= 1) { s += __shfl_down(s, o); d += __shfl_down(d, o); }
        if (t == 0) { a_s2[n0 + r] = s; a_d2[n0 + r] = d; }
    }
}

// ============ Layer 2 fused softmax+aggregate + b2 -> out ============
__global__ __launch_bounds__(64) void k_agg2_fused(const int* __restrict__ rowptr,
    const int* __restrict__ csr_src, const float* __restrict__ a_s2,
    const float* __restrict__ a_d2, const __hip_bfloat16* __restrict__ h3b,
    const float* __restrict__ b2, float* __restrict__ out)
{
    const int dst = blockIdx.x, t = threadIdx.x;
    const int start = rowptr[dst], end = rowptr[dst + 1];
    __shared__ int   s_src[64];
    __shared__ float s_ex[64];
    float ad = a_d2[dst];
    float den = 0.f, acc = 0.f;

    for (int base = start; base < end; base += 64) {
        int nloc = end - base; if (nloc > 64) nloc = 64;
        if (t < nloc) {
            int src = csr_src[base + t];
            s_src[t] = src;
            float e = a_s2[src] + ad;
            e = e > 0.f ? e : NEG_SLOPE * e;
            float ex = expf(e);
            s_ex[t] = ex;
            den += ex;
        }
        __syncthreads();
        int j = 0;
        for (; j + 3 < nloc; j += 4) {
            float vA = __bfloat162float(h3b[(size_t)s_src[j]     * 64 + t]);
            float vB = __bfloat162float(h3b[(size_t)s_src[j + 1] * 64 + t]);
            float vC = __bfloat162float(h3b[(size_t)s_src[j + 2] * 64 + t]);
            float vD = __bfloat162float(h3b[(size_t)s_src[j + 3] * 64 + t]);
            acc += s_ex[j] * vA + s_ex[j + 1] * vB + s_ex[j + 2] * vC + s_ex[j + 3] * vD;
        }
        for (; j < nloc; ++j)
            acc += s_ex[j] * __bfloat162float(h3b[(size_t)s_src[j] * 64 + t]);
        __syncthreads();
    }
#pragma unroll
    for (int o = 1; o < 64; o <<= 1) den += __shfl_xor(den, o);   // butterfly: all lanes get total
    out[(size_t)dst * 64 + t] = acc / den + b2[t];
}

extern "C" void kernel_launch(void* const* d_in, const int* in_sizes, int n_in,
                              void* d_out, int out_size, void* d_ws, size_t ws_size,
                              hipStream_t stream)
{
    const float* x   = (const float*)d_in[0];
    const int*   ei  = (const int*)d_in[1];
    const float* W1  = (const float*)d_in[2];
    const float* as1 = (const float*)d_in[3];
    const float* ad1 = (const float*)d_in[4];
    const float* b1  = (const float*)d_in[5];
    const float* W2  = (const float*)d_in[6];
    const float* as2 = (const float*)d_in[7];
    const float* ad2 = (const float*)d_in[8];
    const float* b2  = (const float*)d_in[9];
    float* out = (float*)d_out;

    const int N = in_sizes[0] / 128;      // 50000
    const int E = in_sizes[1] / 2;        // 800000
    const int M = E + N;                  // edges + self loops
    const int NB = (N + 255) / 256;       // 196 scan blocks

    // ---- workspace layout (256B-aligned), ~63 MB ----
    char* w = (char*)d_ws;
    size_t o = 0;
    auto alloc = [&](size_t bytes) { size_t r = o; o = (o + bytes + 255) & ~(size_t)255; return r; };
    __hip_bfloat16* h1b   = (__hip_bfloat16*)(w + alloc((size_t)N * 256 * 2)); // 25.6 MB
    float* a_s1           = (float*)(w + alloc((size_t)N * 4 * 4));
    float* a_d1           = (float*)(w + alloc((size_t)N * 4 * 4));
    __hip_bfloat16* h2b   = (__hip_bfloat16*)(w + alloc((size_t)N * 256 * 2)); // 25.6 MB
    __hip_bfloat16* h3b   = (__hip_bfloat16*)(w + alloc((size_t)N * 64 * 2));  // 6.4 MB
    float* a_s2           = (float*)(w + alloc((size_t)N * 4));
    float* a_d2           = (float*)(w + alloc((size_t)N * 4));
    int* deg              = (int*)(w + alloc((size_t)N * 4));
    int* cnt              = (int*)(w + alloc((size_t)N * 4));
    int* rowptr           = (int*)(w + alloc((size_t)(N + 1) * 4));
    int* excl             = (int*)(w + alloc((size_t)N * 4));
    int* bsum             = (int*)(w + alloc((size_t)NB * 4));
    int* boff             = (int*)(w + alloc((size_t)NB * 4));
    int* csr_src          = (int*)(w + alloc((size_t)M * 4));                  // 3.4 MB

    // ---- CSR build (shared by both layers) ----
    hipMemsetAsync(deg, 0, (size_t)N * 4, stream);
    hipMemsetAsync(cnt, 0, (size_t)N * 4, stream);
    k_hist<<<(M + 255) / 256, 256, 0, stream>>>(ei, E, M, deg);
    k_scan1<<<NB, 256, 0, stream>>>(deg, N, excl, bsum);
    k_scan2<<<1, 256, 0, stream>>>(bsum, NB, boff);
    k_scan3<<<NB, 256, 0, stream>>>(excl, boff, N, M, rowptr);
    k_scatter<<<(M + 255) / 256, 256, 0, stream>>>(ei, E, M, rowptr, cnt, csr_src);

    // ---- layer 1 ----
    k_gemm1_att<<<N / 8, 256, 0, stream>>>(x, W1, as1, ad1, h1b, a_s1, a_d1);
    k_agg1_fused<<<N, 128, 0, stream>>>(rowptr, csr_src, a_s1, a_d1, h1b, b1, h2b);

    // ---- layer 2 ----
    k_gemm2_att<<<(N + 15) / 16, 64, 0, stream>>>(h2b, W2, as2, ad2, h3b, a_s2, a_d2);
    k_agg2_fused<<<N, 64, 0, stream>>>(rowptr, csr_src, a_s2, a_d2, h3b, b2, out);
}